// Round 9
// baseline (1876.637 us; speedup 1.0000x reference)
//
#include <hip/hip_runtime.h>

// Problem constants
#define BATCH 256
#define SEQ   128
#define HDIM  1024
#define RS    100      // padded row stride (dwords) of split-K LDS buffer

typedef __attribute__((ext_vector_type(8))) short bf16x8;
typedef __attribute__((ext_vector_type(4))) short s16x4;
typedef __attribute__((ext_vector_type(4))) float f32x4;

__device__ __forceinline__ short f2bf(float f) {
    union { float f; unsigned u; } x; x.f = f;
    unsigned r = x.u + 0x7fffu + ((x.u >> 16) & 1u);   // RNE
    return (short)(r >> 16);
}

// LLC-coherent ops (sc0 sc1): bypass L1+L2, coherent at Infinity Cache.
__device__ __forceinline__ void st_llc_b64(short* p, s16x4 v) {
    asm volatile("global_store_dwordx2 %0, %1, off sc0 sc1" :: "v"(p), "v"(v) : "memory");
}
__device__ __forceinline__ void st_llc_b32(unsigned* p, unsigned v) {
    asm volatile("global_store_dword %0, %1, off sc0 sc1" :: "v"(p), "v"(v) : "memory");
}
#define LDH(dst, p, OFF) \
    asm volatile("global_load_dwordx4 %0, %1, off offset:" OFF " sc0 sc1" \
                 : "=v"(dst) : "v"(p))

// ---------------------------------------------------------------------------
// Kernel 1: convert W_ih, W_hh (f32 (3072,1024)) AND x = concat(base,visual)
// (f32, K-major target) to bf16.  xb[(k*256+b)*1024 + c] — rows grouped by
// step so each gru block's 32 A-rows for step k are contiguous and L2-shared
// across its group.  All reads/writes coalesced; one float4 -> s16x4/thread.
__global__ void cvt_all(const float* __restrict__ wih, const float* __restrict__ whh,
                        const float* __restrict__ base, const float* __restrict__ vis,
                        short* __restrict__ wihb, short* __restrict__ whhb,
                        short* __restrict__ xb) {
    const int i = blockIdx.x * 256 + threadIdx.x;
    if (i < 1572864) {                       // weights: 2 x 786432 float4
        const float* s; short* d; int j;
        if (i < 786432) { s = wih; d = wihb; j = i; }
        else            { s = whh; d = whhb; j = i - 786432; }
        const float4 v = *((const float4*)s + j);
        s16x4 o;
        o[0] = f2bf(v.x); o[1] = f2bf(v.y); o[2] = f2bf(v.z); o[3] = f2bf(v.w);
        *(s16x4*)(d + (size_t)j * 4) = o;
    } else {                                 // x: 8388608 float4
        const int j = i - 1572864;
        const int e0 = j * 4;                // element offset in xb
        const int r = e0 >> 10;              // r = k*256 + b
        const int c = e0 & 1023;
        const int b = r & 255, k = r >> 8;
        const float* s = (c < 256)
            ? (base + (size_t)(b * 128 + k) * 256 + c)
            : (vis  + (size_t)(b * 128 + k) * 768 + (c - 256));
        const float4 v = *(const float4*)s;
        s16x4 o;
        o[0] = f2bf(v.x); o[1] = f2bf(v.y); o[2] = f2bf(v.z); o[3] = f2bf(v.w);
        *(s16x4*)(xb + (size_t)e0) = o;
    }
}

// ---------------------------------------------------------------------------
// Kernel 2: persistent GRU recurrence with FUSED x-projection.
// 256 blocks (1/CU) x 256 threads; block = (bt 0..7, ct 0..31):
// 32 batch rows x 32 h-cols (96 gate cols).  W_hh slice in registers.
// h-exchange protocol: EXACT R0 (716us, proven 3x) — packed flag line per
// group, all-wave sc0sc1 poll, h store + vmcnt(0) drain + syncthreads +
// tid0 flag.  ZERO new sync semantics (R1-R8 lesson: every sync-leg tweak
// regressed; the topology is at its comm floor).
// NEW: x_proj is no longer precomputed by a standalone GEMM.  Each block
// computes its own 32x96 x-projection slice for step t+1 (96 MFMAs, same
// shape as the h-GEMM, W_ih fragments streamed from L2) right AFTER
// publishing h(t+1) — inside the ~9000-cycle exchange wait window, where
// the block was previously idle.  x has no h dependence, so this work is
// latency-free if it fits the window; the 460us gemm_xproj disappears.
// Register discipline: A0/A1 and acc are REUSED between the h-GEMM and the
// XP-GEMM (disjoint lifetimes) to stay under the VGPR cliff.
__global__ __launch_bounds__(256, 1) void gru_rec(
    const short* __restrict__ xb,   const short* __restrict__ wihb,
    const short* __restrict__ whhb, const float* __restrict__ bih,
    const float* __restrict__ bhh,  short* __restrict__ hbuf,   // 2 x 256*1024 bf16, zeroed
    float* __restrict__ out, unsigned* __restrict__ flags)      // 8*32 flags, zeroed
{
    __shared__ float red[128 * RS];   // 51200 B split-K partials, padded stride
    const int tid = threadIdx.x;
    const int bid = blockIdx.x;
    const int bt = bid >> 5;       // batch group 0..7
    const int ct = bid & 31;       // col block  0..31
    const int lane = tid & 63, w = tid >> 6;
    const int l15 = lane & 15, quad = lane >> 4;
    const int bm0 = bt * 32;
    const int kbase = w * 256 + quad * 8;   // this wave's K-chunk

    // persistent W_hh fragments (192 VGPRs) + streamed W_ih base pointers
    bf16x8 Bf[6][8];
    const short* wp[6];
#pragma unroll
    for (int g = 0; g < 6; ++g) {
        const size_t col = (size_t)((g >> 1) * 1024 + ct * 32 + (g & 1) * 16 + l15);
        wp[g] = wihb + col * 1024 + kbase;
#pragma unroll
        for (int kk = 0; kk < 8; ++kk)
            Bf[g][kk] = *(const bf16x8*)(whhb + col * 1024 + kbase + kk * 32);
    }

    // epilogue ownership: 1 row x 4 consecutive cols per thread
    const int er = tid >> 3;             // row within group, 0..31
    const int ec0 = (tid & 7) * 4;       // first col, 0..28
    const f32x4 bhr = *(const f32x4*)(bhh + ct * 32 + ec0);
    const f32x4 bhz = *(const f32x4*)(bhh + 1024 + ct * 32 + ec0);
    const f32x4 bhn = *(const f32x4*)(bhh + 2048 + ct * 32 + ec0);
    const f32x4 bir = *(const f32x4*)(bih + ct * 32 + ec0);
    const f32x4 biz = *(const f32x4*)(bih + 1024 + ct * 32 + ec0);
    const f32x4 bin_ = *(const f32x4*)(bih + 2048 + ct * 32 + ec0);

    unsigned* const myflag = flags + bt * 32 + ct;
    const unsigned* const pollp = flags + bt * 32 + (lane & 31);

    float hold[4] = {0.f, 0.f, 0.f, 0.f};
    // shared register blocks (reused by both GEMMs — disjoint lifetimes)
    bf16x8 A0[8], A1[8];
    f32x4 acc[2][6];
    f32x4 xg[3];                       // this step's x-projection (f32)

    // XP(t): compute this block's 32x96 x-projection slice for step t -> xg.
    // Runs inside the exchange wait window.  Uses red[] (free there: last
    // h-read was before the publication barrier).
    auto XP = [&](int t) {
        const short* xa0 = xb + ((size_t)(t * 256 + bm0 + l15)) * 1024 + kbase;
        const short* xa1 = xa0 + 16 * 1024;
#pragma unroll
        for (int kk = 0; kk < 8; ++kk) {
            A0[kk] = *(const bf16x8*)(xa0 + kk * 32);
            A1[kk] = *(const bf16x8*)(xa1 + kk * 32);
        }
#pragma unroll
        for (int i = 0; i < 2; ++i)
#pragma unroll
            for (int g = 0; g < 6; ++g) acc[i][g] = (f32x4){0.f, 0.f, 0.f, 0.f};
#pragma unroll
        for (int kk = 0; kk < 8; ++kk) {
#pragma unroll
            for (int g = 0; g < 6; ++g) {
                const bf16x8 wf = *(const bf16x8*)(wp[g] + kk * 32);
                acc[0][g] = __builtin_amdgcn_mfma_f32_16x16x32_bf16(A0[kk], wf, acc[0][g], 0, 0, 0);
                acc[1][g] = __builtin_amdgcn_mfma_f32_16x16x32_bf16(A1[kk], wf, acc[1][g], 0, 0, 0);
            }
        }
#pragma unroll
        for (int i = 0; i < 2; ++i)
#pragma unroll
            for (int g = 0; g < 6; ++g) {
                const int c96 = (g >> 1) * 32 + (g & 1) * 16 + l15;
                const int rb = w * 32 + i * 16 + quad * 4;
#pragma unroll
                for (int r = 0; r < 4; ++r)
                    red[(rb + r) * RS + c96] = acc[i][g][r];
            }
        __syncthreads();               // xp partials written -> readable
        xg[0] = bir; xg[1] = biz; xg[2] = bin_;
#pragma unroll
        for (int ww = 0; ww < 4; ++ww) {
            const float* rbp = &red[(ww * 32 + er) * RS];
            xg[0] += *(const f32x4*)(rbp + ec0);
            xg[1] += *(const f32x4*)(rbp + 32 + ec0);
            xg[2] += *(const f32x4*)(rbp + 64 + ec0);
        }
        __syncthreads();               // red free before next h-partials write
    };

    XP(0);                             // prologue: x-projection for step 0

    for (int step = 0; step < 128; ++step) {
        // --- wait for step's h (producers flagged `step`); step 0 pre-zeroed ---
        if (step > 0) {
            const unsigned tgt = (unsigned)step;
            unsigned fv;
            do {
                asm volatile("global_load_dword %0, %1, off sc0 sc1" : "=v"(fv) : "v"(pollp));
                asm volatile("s_waitcnt vmcnt(0)" : "+v"(fv) :: "memory");
            } while (__ballot(fv < tgt));
        }
        const short* hr_ = hbuf + (size_t)(step & 1) * (256 * 1024);
        short* hw_ = hbuf + (size_t)((step + 1) & 1) * (256 * 1024);

        // --- h loads: 16 LLC-bypass b128 loads + rule-18 fence ---
        const short* p0 = hr_ + (size_t)(bm0 + l15) * 1024 + kbase;
        const short* p1 = p0 + 16 * 1024;
        LDH(A0[0], p0, "0");   LDH(A0[1], p0, "64");  LDH(A0[2], p0, "128"); LDH(A0[3], p0, "192");
        LDH(A0[4], p0, "256"); LDH(A0[5], p0, "320"); LDH(A0[6], p0, "384"); LDH(A0[7], p0, "448");
        LDH(A1[0], p1, "0");   LDH(A1[1], p1, "64");  LDH(A1[2], p1, "128"); LDH(A1[3], p1, "192");
        LDH(A1[4], p1, "256"); LDH(A1[5], p1, "320"); LDH(A1[6], p1, "384"); LDH(A1[7], p1, "448");
        asm volatile("s_waitcnt vmcnt(0)" ::: "memory");
        __builtin_amdgcn_sched_barrier(0);

#pragma unroll
        for (int i = 0; i < 2; ++i)
#pragma unroll
            for (int g = 0; g < 6; ++g) acc[i][g] = (f32x4){0.f, 0.f, 0.f, 0.f};
#pragma unroll
        for (int kk = 0; kk < 8; ++kk) {
#pragma unroll
            for (int g = 0; g < 6; ++g) {
                acc[0][g] = __builtin_amdgcn_mfma_f32_16x16x32_bf16(A0[kk], Bf[g][kk], acc[0][g], 0, 0, 0);
                acc[1][g] = __builtin_amdgcn_mfma_f32_16x16x32_bf16(A1[kk], Bf[g][kk], acc[1][g], 0, 0, 0);
            }
        }
        // split-K partials -> LDS (padded stride: 2-way max, conflict-free)
#pragma unroll
        for (int i = 0; i < 2; ++i)
#pragma unroll
            for (int g = 0; g < 6; ++g) {
                const int c96 = (g >> 1) * 32 + (g & 1) * 16 + l15;
                const int rb = w * 32 + i * 16 + quad * 4;
#pragma unroll
                for (int r = 0; r < 4; ++r)
                    red[(rb + r) * RS + c96] = acc[i][g][r];
            }
        __syncthreads();
        // reduce 4 split-K partials + gates + state update
        f32x4 sr = bhr, sz = bhz, sn = bhn;
#pragma unroll
        for (int ww = 0; ww < 4; ++ww) {
            const float* rbp = &red[(ww * 32 + er) * RS];
            sr += *(const f32x4*)(rbp + ec0);
            sz += *(const f32x4*)(rbp + 32 + ec0);
            sn += *(const f32x4*)(rbp + 64 + ec0);
        }
        s16x4 hpk;
#pragma unroll
        for (int i = 0; i < 4; ++i) {
            const float xr = xg[0][i];
            const float xz = xg[1][i];
            const float xnv = xg[2][i];
            const float rg = 1.f / (1.f + __expf(-(xr + sr[i])));
            const float zg = 1.f / (1.f + __expf(-(xz + sz[i])));
            const float e2 = __expf(2.f * (xnv + rg * sn[i]));
            const float ng = 1.f - 2.f / (e2 + 1.f);   // tanh, overflow-safe
            const float hv = (1.f - zg) * ng + zg * hold[i];
            hold[i] = hv;
            hpk[i] = f2bf(hv);
        }
        if (step < 127) {
            // --- publish h(t+1): EXACT R0 protocol ---
            st_llc_b64(&hw_[(size_t)(bm0 + er) * 1024 + ct * 32 + ec0], hpk);
            asm volatile("s_waitcnt vmcnt(0)" ::: "memory");   // drain h store
            __builtin_amdgcn_sched_barrier(0);
            __syncthreads();                                   // all waves drained
            if (tid == 0) st_llc_b32(myflag, (unsigned)(step + 1));
            // --- fill the exchange wait window with next step's x-projection ---
            XP(step + 1);
        } else {
            __syncthreads();   // uniformity on last step (cheap)
        }
    }
    float4 o4; o4.x = hold[0]; o4.y = hold[1]; o4.z = hold[2]; o4.w = hold[3];
    *(float4*)(out + (size_t)(bm0 + er) * 1024 + ct * 32 + ec0) = o4;
}

// ---------------------------------------------------------------------------
extern "C" void kernel_launch(void* const* d_in, const int* in_sizes, int n_in,
                              void* d_out, int out_size, void* d_ws, size_t ws_size,
                              hipStream_t stream) {
    (void)in_sizes; (void)n_in; (void)out_size; (void)ws_size;
    const float* base = (const float*)d_in[0];
    const float* vis  = (const float*)d_in[1];
    const float* wih  = (const float*)d_in[2];
    const float* whh  = (const float*)d_in[3];
    const float* bih  = (const float*)d_in[4];
    const float* bhh  = (const float*)d_in[5];

    char* ws = (char*)d_ws;
    short*    xb   = (short*)(ws + 0);                    //  67108864 B (x bf16, K-major)
    short*    wihb = (short*)(ws + 201326592);            //   6291456 B
    short*    whhb = (short*)(ws + 207618048);            //   6291456 B
    short*    hbuf = (short*)(ws + 213909504);            //   1048576 B (ping-pong)
    unsigned* flg  = (unsigned*)(ws + 214958080);         //      4096 B
    // workspace footprint byte-identical to the proven R0 map.

    (void)hipMemsetAsync(hbuf, 0, 1048576, stream);       // h0 = 0 (both buffers)
    (void)hipMemsetAsync(flg, 0, 4096, stream);           // flags

    // weights (1572864 float4) + x (8388608 float4) = 9961472 / 256 = 38912
    cvt_all<<<dim3(38912), dim3(256), 0, stream>>>(wih, whh, base, vis, wihb, whhb, xb);
    gru_rec<<<dim3(256), dim3(256), 0, stream>>>(xb, wihb, whhb, bih, bhh, hbuf,
                                                 (float*)d_out, flg);
}

// Round 10
// 1634.465 us; speedup vs baseline: 1.1482x; 1.1482x over previous
//
#include <hip/hip_runtime.h>

// Problem constants
#define BATCH 256
#define SEQ   128
#define HDIM  1024
#define RS    100      // padded row stride (dwords) of split-K LDS buffer

typedef __attribute__((ext_vector_type(8))) short bf16x8;
typedef __attribute__((ext_vector_type(4))) short s16x4;
typedef __attribute__((ext_vector_type(4))) float f32x4;

__device__ __forceinline__ short f2bf(float f) {
    union { float f; unsigned u; } x; x.f = f;
    unsigned r = x.u + 0x7fffu + ((x.u >> 16) & 1u);   // RNE
    return (short)(r >> 16);
}

// LLC-coherent ops (sc0 sc1): bypass L1+L2, coherent at Infinity Cache.
__device__ __forceinline__ void st_llc_b64(short* p, s16x4 v) {
    asm volatile("global_store_dwordx2 %0, %1, off sc0 sc1" :: "v"(p), "v"(v) : "memory");
}
__device__ __forceinline__ void st_llc_b32(unsigned* p, unsigned v) {
    asm volatile("global_store_dword %0, %1, off sc0 sc1" :: "v"(p), "v"(v) : "memory");
}
#define LDH(dst, p, OFF) \
    asm volatile("global_load_dwordx4 %0, %1, off offset:" OFF " sc0 sc1" \
                 : "=v"(dst) : "v"(p))

// ---------------------------------------------------------------------------
// Kernel 1: convert W_ih, W_hh (f32 (3072,1024)) to bf16 row-major, and
// x = concat(base,visual) to bf16 in MFMA-FRAGMENT order:
//   chunk = (k*8 + bt)*64 + (half*4 + w)*8 + kk   (1 KB per chunk)
//   byte  = chunk*1024 + lane*16,  lane = quad*16 + l15
// holding rows bt*32 + half*16 + l15, cols w*256 + quad*8 + kk*32 + 0..7 —
// exactly the A-fragment each gru wave consumes, so XP's loads are fully
// coalesced 1KB wave-transactions (R9's 16-segment gathers are gone).
__global__ void cvt_all(const float* __restrict__ wih, const float* __restrict__ whh,
                        const float* __restrict__ base, const float* __restrict__ vis,
                        short* __restrict__ wihb, short* __restrict__ whhb,
                        short* __restrict__ xbf) {
    const int i = blockIdx.x * 256 + threadIdx.x;
    if (i < 1572864) {                       // weights: 2 x 786432 float4
        const float* s; short* d; int j;
        if (i < 786432) { s = wih; d = wihb; j = i; }
        else            { s = whh; d = whhb; j = i - 786432; }
        const float4 v = *((const float4*)s + j);
        s16x4 o;
        o[0] = f2bf(v.x); o[1] = f2bf(v.y); o[2] = f2bf(v.z); o[3] = f2bf(v.w);
        *(s16x4*)(d + (size_t)j * 4) = o;
    } else {                                 // x: 4194304 threads, 8 f32 each
        const int jx = i - 1572864;
        const int c0 = (jx & 127) * 8;       // col 0..1016, step 8
        const int rb = jx >> 7;              // k*256 + b
        const int k = rb >> 8, b = rb & 255;
        const float* s = (c0 < 256)
            ? (base + (size_t)(b * 128 + k) * 256 + c0)
            : (vis  + (size_t)(b * 128 + k) * 768 + (c0 - 256));
        const float4 v0 = ((const float4*)s)[0];
        const float4 v1 = ((const float4*)s)[1];
        bf16x8 o;
        o[0] = f2bf(v0.x); o[1] = f2bf(v0.y); o[2] = f2bf(v0.z); o[3] = f2bf(v0.w);
        o[4] = f2bf(v1.x); o[5] = f2bf(v1.y); o[6] = f2bf(v1.z); o[7] = f2bf(v1.w);
        const int chunk = (k * 8 + (b >> 5)) * 64 + (((b >> 4) & 1) * 4 + (c0 >> 8)) * 8
                        + ((c0 >> 5) & 7);
        const int lane16 = ((c0 >> 3) & 3) * 16 + (b & 15);
        *(bf16x8*)((char*)xbf + (size_t)chunk * 1024 + lane16 * 16) = o;
    }
}

// ---------------------------------------------------------------------------
// Kernel 2: persistent GRU recurrence with FUSED x-projection, both weight
// matrices in registers.  256 blocks (1/CU) x 256 threads; block =
// (bt 0..7, ct 0..31): 32 batch rows x 32 h-cols (96 gate cols).
// R9 lesson: XP streaming W_ih from LLC every step (6.4 GB aggregate) was
// the regression — W_ih now lives in Wf[6][8] (192 VGPRs) next to W_hh's
// Bf[6][8].  At 1 wave/SIMD the 512-VGPR budget covers both (est ~490 peak;
// GEMMs restructured as two row-half passes with acc[6], biases in LDS).
// h-exchange protocol: EXACT R0 (716us, proven 3x) — packed flag line per
// group, all-wave sc0sc1 poll, h store + vmcnt(0) drain + syncthreads +
// tid0 flag.  XP (16 coalesced xbf loads + 96 MFMAs + LDS reduce) runs in
// the exchange wait window right after flag publication.
__global__ __launch_bounds__(256, 1) void gru_rec(
    const short* __restrict__ xbf,  const short* __restrict__ wihb,
    const short* __restrict__ whhb, const float* __restrict__ bih,
    const float* __restrict__ bhh,  short* __restrict__ hbuf,   // 2 x 256*1024 bf16, zeroed
    float* __restrict__ out, unsigned* __restrict__ flags)      // 8*32 flags, zeroed
{
    __shared__ float red[128 * RS];   // 51200 B split-K partials, padded stride
    __shared__ float bias[192];       // [g*32+c]: g 0..2 = bih r,z,n; 3..5 = bhh
    const int tid = threadIdx.x;
    const int bid = blockIdx.x;
    const int bt = bid >> 5;       // batch group 0..7
    const int ct = bid & 31;       // col block  0..31
    const int lane = tid & 63, w = tid >> 6;
    const int l15 = lane & 15, quad = lane >> 4;
    const int bm0 = bt * 32;
    const int kbase = w * 256 + quad * 8;   // this wave's K-chunk

    // persistent weight fragments: W_hh (Bf) + W_ih (Wf), 192 VGPRs each
    bf16x8 Bf[6][8], Wf[6][8];
#pragma unroll
    for (int g = 0; g < 6; ++g) {
        const size_t col = (size_t)((g >> 1) * 1024 + ct * 32 + (g & 1) * 16 + l15);
#pragma unroll
        for (int kk = 0; kk < 8; ++kk) {
            Bf[g][kk] = *(const bf16x8*)(whhb + col * 1024 + kbase + kk * 32);
            Wf[g][kk] = *(const bf16x8*)(wihb + col * 1024 + kbase + kk * 32);
        }
    }

    // epilogue ownership: 1 row x 4 consecutive cols per thread
    const int er = tid >> 3;             // row within group, 0..31
    const int ec0 = (tid & 7) * 4;       // first col, 0..28

    if (tid < 48) {                      // biases -> LDS (saves 24 VGPRs)
        const int g = tid >> 3, c4 = (tid & 7) * 4;
        const float* src = (g < 3) ? (bih + g * 1024) : (bhh + (g - 3) * 1024);
        *(f32x4*)&bias[g * 32 + c4] = *(const f32x4*)(src + ct * 32 + c4);
    }

    unsigned* const myflag = flags + bt * 32 + ct;
    const unsigned* const pollp = flags + bt * 32 + (lane & 31);

    float hold[4] = {0.f, 0.f, 0.f, 0.f};
    bf16x8 A0[8], A1[8];               // shared by h-GEMM and XP (disjoint lifetimes)
    f32x4 xg[3];                       // this step's x-projection (f32)

    // one GEMM row-half pass: acc[6] (24 regs), 6 independent MFMA chains
    auto half_pass = [&](const bf16x8* Ah, const bf16x8 (*Bm)[8], int h2) {
        f32x4 a6[6];
#pragma unroll
        for (int g = 0; g < 6; ++g) a6[g] = (f32x4){0.f, 0.f, 0.f, 0.f};
#pragma unroll
        for (int kk = 0; kk < 8; ++kk)
#pragma unroll
            for (int g = 0; g < 6; ++g)
                a6[g] = __builtin_amdgcn_mfma_f32_16x16x32_bf16(Ah[kk], Bm[g][kk], a6[g], 0, 0, 0);
        const int rbase = w * 32 + h2 * 16 + quad * 4;
#pragma unroll
        for (int g = 0; g < 6; ++g) {
            const int c96 = (g >> 1) * 32 + (g & 1) * 16 + l15;
#pragma unroll
            for (int r = 0; r < 4; ++r)
                red[(rbase + r) * RS + c96] = a6[g][r];
        }
    };

    // XP(t): 32x96 x-projection slice for step t -> xg, in the wait window.
    auto XP = [&](int t) {
        const short* xa = xbf + ((size_t)((t * 8 + bt) * 64 + w * 8)) * 512 + lane * 8;
#pragma unroll
        for (int kk = 0; kk < 8; ++kk) {
            A0[kk] = *(const bf16x8*)(xa + kk * 512);
            A1[kk] = *(const bf16x8*)(xa + 16384 + kk * 512);
        }
        half_pass(A0, Wf, 0);
        half_pass(A1, Wf, 1);
        __syncthreads();               // xp partials written -> readable
        xg[0] = *(const f32x4*)&bias[ec0];
        xg[1] = *(const f32x4*)&bias[32 + ec0];
        xg[2] = *(const f32x4*)&bias[64 + ec0];
#pragma unroll
        for (int ww = 0; ww < 4; ++ww) {
            const float* rbp = &red[(ww * 32 + er) * RS];
            xg[0] += *(const f32x4*)(rbp + ec0);
            xg[1] += *(const f32x4*)(rbp + 32 + ec0);
            xg[2] += *(const f32x4*)(rbp + 64 + ec0);
        }
        __syncthreads();               // red free before next h-partials write
    };

    __syncthreads();                   // bias LDS ready
    XP(0);                             // prologue: x-projection for step 0

    for (int step = 0; step < 128; ++step) {
        // --- wait for step's h (producers flagged `step`); step 0 pre-zeroed ---
        if (step > 0) {
            const unsigned tgt = (unsigned)step;
            unsigned fv;
            do {
                asm volatile("global_load_dword %0, %1, off sc0 sc1" : "=v"(fv) : "v"(pollp));
                asm volatile("s_waitcnt vmcnt(0)" : "+v"(fv) :: "memory");
            } while (__ballot(fv < tgt));
        }
        const short* hr_ = hbuf + (size_t)(step & 1) * (256 * 1024);
        short* hw_ = hbuf + (size_t)((step + 1) & 1) * (256 * 1024);

        // --- h loads: 16 LLC-bypass b128 loads + rule-18 fence ---
        const short* p0 = hr_ + (size_t)(bm0 + l15) * 1024 + kbase;
        const short* p1 = p0 + 16 * 1024;
        LDH(A0[0], p0, "0");   LDH(A0[1], p0, "64");  LDH(A0[2], p0, "128"); LDH(A0[3], p0, "192");
        LDH(A0[4], p0, "256"); LDH(A0[5], p0, "320"); LDH(A0[6], p0, "384"); LDH(A0[7], p0, "448");
        LDH(A1[0], p1, "0");   LDH(A1[1], p1, "64");  LDH(A1[2], p1, "128"); LDH(A1[3], p1, "192");
        LDH(A1[4], p1, "256"); LDH(A1[5], p1, "320"); LDH(A1[6], p1, "384"); LDH(A1[7], p1, "448");
        asm volatile("s_waitcnt vmcnt(0)" ::: "memory");
        __builtin_amdgcn_sched_barrier(0);

        half_pass(A0, Bf, 0);
        half_pass(A1, Bf, 1);
        __syncthreads();
        // reduce 4 split-K partials + gates + state update
        f32x4 sr = *(const f32x4*)&bias[96 + ec0];
        f32x4 sz = *(const f32x4*)&bias[128 + ec0];
        f32x4 sn = *(const f32x4*)&bias[160 + ec0];
#pragma unroll
        for (int ww = 0; ww < 4; ++ww) {
            const float* rbp = &red[(ww * 32 + er) * RS];
            sr += *(const f32x4*)(rbp + ec0);
            sz += *(const f32x4*)(rbp + 32 + ec0);
            sn += *(const f32x4*)(rbp + 64 + ec0);
        }
        s16x4 hpk;
#pragma unroll
        for (int i = 0; i < 4; ++i) {
            const float rg = 1.f / (1.f + __expf(-(xg[0][i] + sr[i])));
            const float zg = 1.f / (1.f + __expf(-(xg[1][i] + sz[i])));
            const float e2 = __expf(2.f * (xg[2][i] + rg * sn[i]));
            const float ng = 1.f - 2.f / (e2 + 1.f);   // tanh, overflow-safe
            const float hv = (1.f - zg) * ng + zg * hold[i];
            hold[i] = hv;
            hpk[i] = f2bf(hv);
        }
        if (step < 127) {
            // --- publish h(t+1): EXACT R0 protocol ---
            st_llc_b64(&hw_[(size_t)(bm0 + er) * 1024 + ct * 32 + ec0], hpk);
            asm volatile("s_waitcnt vmcnt(0)" ::: "memory");   // drain h store
            __builtin_amdgcn_sched_barrier(0);
            __syncthreads();                                   // all waves drained
            if (tid == 0) st_llc_b32(myflag, (unsigned)(step + 1));
            // --- fill the exchange wait window with next step's x-projection ---
            XP(step + 1);
        } else {
            __syncthreads();   // uniformity on last step (cheap)
        }
    }
    float4 o4; o4.x = hold[0]; o4.y = hold[1]; o4.z = hold[2]; o4.w = hold[3];
    *(float4*)(out + (size_t)(bm0 + er) * 1024 + ct * 32 + ec0) = o4;
}

// ---------------------------------------------------------------------------
extern "C" void kernel_launch(void* const* d_in, const int* in_sizes, int n_in,
                              void* d_out, int out_size, void* d_ws, size_t ws_size,
                              hipStream_t stream) {
    (void)in_sizes; (void)n_in; (void)out_size; (void)ws_size;
    const float* base = (const float*)d_in[0];
    const float* vis  = (const float*)d_in[1];
    const float* wih  = (const float*)d_in[2];
    const float* whh  = (const float*)d_in[3];
    const float* bih  = (const float*)d_in[4];
    const float* bhh  = (const float*)d_in[5];

    char* ws = (char*)d_ws;
    short*    xbf  = (short*)(ws + 0);                    //  67108864 B (x bf16, fragment order)
    short*    wihb = (short*)(ws + 201326592);            //   6291456 B
    short*    whhb = (short*)(ws + 207618048);            //   6291456 B
    short*    hbuf = (short*)(ws + 213909504);            //   1048576 B (ping-pong)
    unsigned* flg  = (unsigned*)(ws + 214958080);         //      4096 B
    // workspace footprint byte-identical to the proven R0 map.

    (void)hipMemsetAsync(hbuf, 0, 1048576, stream);       // h0 = 0 (both buffers)
    (void)hipMemsetAsync(flg, 0, 4096, stream);           // flags

    // weights 1572864 threads + x 4194304 threads = 5767168 / 256 = 22528
    cvt_all<<<dim3(22528), dim3(256), 0, stream>>>(wih, whh, base, vis, wihb, whhb, xbf);
    gru_rec<<<dim3(256), dim3(256), 0, stream>>>(xbf, wihb, whhb, bih, bhh, hbuf,
                                                 (float*)d_out, flg);
}